// Round 3
// baseline (762.762 us; speedup 1.0000x reference)
//
#include <hip/hip_runtime.h>

#define THREADS 256

// ---- kernels ------------------------------------------------------------

// Zero three N-element float arrays (accumulators + output).
__global__ void k_zero3(float* __restrict__ a, float* __restrict__ b,
                        float* __restrict__ c, int N) {
    int i = blockIdx.x * blockDim.x + threadIdx.x;
    int stride = gridDim.x * blockDim.x;
    for (int v = i; v < N; v += stride) {
        a[v] = 0.f;
        b[v] = 0.f;
        c[v] = 0.f;
    }
}

// In-degree count (self loop added later), accumulated as float.
__global__ void k_deg(const int* __restrict__ dst, int E,
                      float* __restrict__ degf) {
    int i = blockIdx.x * blockDim.x + threadIdx.x;
    int stride = gridDim.x * blockDim.x;
    for (int e = i; e < E; e += stride) {
        atomicAdd(&degf[dst[e]], 1.0f);
    }
}

// dinv[v] = rsqrt(deg[v]+1), in place over the degree buffer.
__global__ void k_dinv(float* __restrict__ degf_to_dinv, int N) {
    int v = blockIdx.x * blockDim.x + threadIdx.x;
    if (v < N) {
        degf_to_dinv[v] = rsqrtf(degf_to_dinv[v] + 1.0f);
    }
}

// acc1[dst[e]] += x[src[e]] * dinv[src[e]]
__global__ void k_edge1(const int* __restrict__ src,
                        const int* __restrict__ dst,
                        const float* __restrict__ x,
                        const float* __restrict__ dinv,
                        float* __restrict__ acc1, int E) {
    int i = blockIdx.x * blockDim.x + threadIdx.x;
    int stride = gridDim.x * blockDim.x;
    for (int e = i; e < E; e += stride) {
        int s = src[e];
        float v = x[s] * dinv[s];
        atomicAdd(&acc1[dst[e]], v);
    }
}

// agg = dinv*(acc1 + x*dinv);  z = sum_f relu(W1[f]*agg+b1[f])*W2[f];
// zy = z*dinv  (the pre-scaled layer-2 message)
__global__ void k_node2(const float* __restrict__ dinv,
                        const float* __restrict__ acc1,
                        const float* __restrict__ x,
                        const float* __restrict__ W1,
                        const float* __restrict__ b1,
                        const float* __restrict__ W2,
                        float* __restrict__ zy, int N, int F) {
    int v = blockIdx.x * blockDim.x + threadIdx.x;
    if (v < N) {
        float d = dinv[v];
        float agg = d * (acc1[v] + x[v] * d);
        float z = 0.f;
        for (int f = 0; f < F; ++f) {
            float h = fmaf(W1[f], agg, b1[f]);
            h = h > 0.f ? h : 0.f;
            z = fmaf(h, W2[f], z);
        }
        zy[v] = z * d;
    }
}

// out[dst[e]] += zy[src[e]]   (accumulate layer 2 directly into d_out)
__global__ void k_edge2(const int* __restrict__ src,
                        const int* __restrict__ dst,
                        const float* __restrict__ zy,
                        float* __restrict__ out, int E) {
    int i = blockIdx.x * blockDim.x + threadIdx.x;
    int stride = gridDim.x * blockDim.x;
    for (int e = i; e < E; e += stride) {
        float v = zy[src[e]];
        atomicAdd(&out[dst[e]], v);
    }
}

// out[v] = dinv*(out[v] + zy[v]) + b2   (in place)
__global__ void k_node3(const float* __restrict__ dinv,
                        const float* __restrict__ zy,
                        const float* __restrict__ b2,
                        float* __restrict__ out, int N) {
    int v = blockIdx.x * blockDim.x + threadIdx.x;
    if (v < N) {
        out[v] = fmaf(dinv[v], out[v] + zy[v], b2[0]);
    }
}

// ---- launch -------------------------------------------------------------

extern "C" void kernel_launch(void* const* d_in, const int* in_sizes, int n_in,
                              void* d_out, int out_size, void* d_ws, size_t ws_size,
                              hipStream_t stream) {
    const float* x  = (const float*)d_in[0];
    const int*   ei = (const int*)d_in[1];   // harness passes integers as int32
    const float* W1 = (const float*)d_in[2];
    const float* b1 = (const float*)d_in[3];
    const float* W2 = (const float*)d_in[4];
    const float* b2 = (const float*)d_in[5];
    float* out = (float*)d_out;

    const int N = in_sizes[0];          // x is [N,1] -> N
    const int E = in_sizes[1] / 2;      // edge_index is [2,E]
    const int F = in_sizes[2];          // hidden width (16)

    const int* src = ei;
    const int* dst = ei + E;

    // workspace layout (12 MB total): [degf->dinv | acc1 | zy], each N*4 B.
    char* ws = (char*)d_ws;
    float* dinv = (float*)(ws);                     // holds degf, then dinv
    float* acc1 = (float*)(ws + (size_t)N * 4);
    float* zy   = (float*)(ws + (size_t)N * 8);

    int nodeBlocks = (N + THREADS - 1) / THREADS;
    int edgeBlocks = (E + THREADS - 1) / THREADS;
    if (edgeBlocks > 2048) edgeBlocks = 2048;  // grid-stride the rest

    k_zero3<<<2048, THREADS, 0, stream>>>(dinv, acc1, out, N);
    k_deg  <<<edgeBlocks, THREADS, 0, stream>>>(dst, E, dinv);
    k_dinv <<<nodeBlocks, THREADS, 0, stream>>>(dinv, N);
    k_edge1<<<edgeBlocks, THREADS, 0, stream>>>(src, dst, x, dinv, acc1, E);
    k_node2<<<nodeBlocks, THREADS, 0, stream>>>(dinv, acc1, x, W1, b1, W2, zy, N, F);
    k_edge2<<<edgeBlocks, THREADS, 0, stream>>>(src, dst, zy, out, E);
    k_node3<<<nodeBlocks, THREADS, 0, stream>>>(dinv, zy, b2, out, N);
}

// Round 4
// 165.340 us; speedup vs baseline: 4.6133x; 4.6133x over previous
//
#include <hip/hip_runtime.h>

#define THREADS 256
#define PB 256          // partition blocks for hist/scatter (must == 256)
#define BT 512          // threads for bucket kernels
#define BSH 12          // bucket shift: 4096 nodes per bucket
#define BSZ 4096

// ===================== binned (atomic-free) pipeline =====================

// Per-block histogram of dst buckets. bh layout: [bucket][block] = bh[j*PB+b].
__global__ void k_hist(const int* __restrict__ dst, int E, int per,
                       unsigned* __restrict__ bh, int NB) {
    int b = blockIdx.x, tid = threadIdx.x;
    __shared__ unsigned h[256];
    h[tid] = 0u;
    __syncthreads();
    int lo = b * per;
    int hi = lo + per; if (hi > E) hi = E;
    for (int e = lo + tid; e < hi; e += 256)
        atomicAdd(&h[dst[e] >> BSH], 1u);
    __syncthreads();
    if (tid < NB) bh[tid * PB + b] = h[tid];
}

// Exclusive scan down each bucket column (over the 256 partition blocks).
__global__ void k_colscan(unsigned* __restrict__ bh,
                          unsigned* __restrict__ totals) {
    int j = blockIdx.x, tid = threadIdx.x;
    __shared__ unsigned sh[256];
    unsigned v = bh[j * PB + tid];
    sh[tid] = v;
    __syncthreads();
    for (int off = 1; off < 256; off <<= 1) {
        unsigned t = (tid >= off) ? sh[tid - off] : 0u;
        __syncthreads();
        sh[tid] += t;
        __syncthreads();
    }
    bh[j * PB + tid] = sh[tid] - v;      // exclusive within column
    if (tid == 255) totals[j] = sh[255]; // bucket total
}

// Exclusive scan of bucket totals -> bucketStart[0..NB] (bucketStart[NB]=E).
__global__ void k_scantot(const unsigned* __restrict__ totals,
                          unsigned* __restrict__ bstart, int NB) {
    int tid = threadIdx.x;
    __shared__ unsigned sh[256];
    unsigned v = (tid < NB) ? totals[tid] : 0u;
    sh[tid] = v;
    __syncthreads();
    for (int off = 1; off < 256; off <<= 1) {
        unsigned t = (tid >= off) ? sh[tid - off] : 0u;
        __syncthreads();
        sh[tid] += t;
        __syncthreads();
    }
    if (tid <= NB) bstart[tid] = sh[tid] - v;
}

// Scatter edges into bucket-contiguous packed records: src(20b) | dl(12b)<<20.
__global__ void k_scatter(const int* __restrict__ src,
                          const int* __restrict__ dst, int E, int per,
                          const unsigned* __restrict__ bh,
                          const unsigned* __restrict__ bstart,
                          unsigned* __restrict__ packed, int NB) {
    int b = blockIdx.x, tid = threadIdx.x;
    __shared__ unsigned cur[256];
    if (tid < NB) cur[tid] = bstart[tid] + bh[tid * PB + b];
    __syncthreads();
    int lo = b * per;
    int hi = lo + per; if (hi > E) hi = E;
    for (int e = lo + tid; e < hi; e += 256) {
        int d = dst[e];
        int j = d >> BSH;
        unsigned pos = atomicAdd(&cur[j], 1u);
        packed[pos] = (unsigned)src[e] | ((unsigned)(d & (BSZ - 1)) << 20);
    }
}

// Per-bucket degree count in LDS -> dinv & y = x*dinv (exclusive node range).
__global__ void k_deg(const unsigned* __restrict__ packed,
                      const unsigned* __restrict__ bstart,
                      const float* __restrict__ x,
                      float* __restrict__ dinv, float* __restrict__ y, int N) {
    int j = blockIdx.x;
    __shared__ unsigned cnt[BSZ];
    for (int t = threadIdx.x; t < BSZ; t += BT) cnt[t] = 0u;
    __syncthreads();
    unsigned e0 = bstart[j], e1 = bstart[j + 1];
    for (unsigned e = e0 + threadIdx.x; e < e1; e += BT)
        atomicAdd(&cnt[packed[e] >> 20], 1u);
    __syncthreads();
    int base = j << BSH;
    for (int t = threadIdx.x; t < BSZ; t += BT) {
        int v = base + t;
        if (v < N) {
            float d = rsqrtf((float)cnt[t] + 1.0f);
            dinv[v] = d;
            y[v] = x[v] * d;
        }
    }
}

// Layer-1 aggregate (LDS) + fused per-node MLP -> zy = z*dinv.
__global__ void k_acc1(const unsigned* __restrict__ packed,
                       const unsigned* __restrict__ bstart,
                       const float* __restrict__ y,
                       const float* __restrict__ dinv,
                       const float* __restrict__ W1,
                       const float* __restrict__ b1,
                       const float* __restrict__ W2,
                       float* __restrict__ zy, int N, int F) {
    int j = blockIdx.x;
    __shared__ float acc[BSZ];
    __shared__ float w1s[64], b1s[64], w2s[64];
    for (int t = threadIdx.x; t < BSZ; t += BT) acc[t] = 0.f;
    if (threadIdx.x < (unsigned)F) {
        w1s[threadIdx.x] = W1[threadIdx.x];
        b1s[threadIdx.x] = b1[threadIdx.x];
        w2s[threadIdx.x] = W2[threadIdx.x];
    }
    __syncthreads();
    unsigned e0 = bstart[j], e1 = bstart[j + 1];
    unsigned e = e0 + threadIdx.x;
    // 4-deep unroll: keep 4 gathers in flight.
    for (; e + 3u * BT < e1; e += 4u * BT) {
        unsigned p0 = packed[e], p1 = packed[e + BT];
        unsigned p2 = packed[e + 2u * BT], p3 = packed[e + 3u * BT];
        float v0 = y[p0 & 0xFFFFFu], v1 = y[p1 & 0xFFFFFu];
        float v2 = y[p2 & 0xFFFFFu], v3 = y[p3 & 0xFFFFFu];
        atomicAdd(&acc[p0 >> 20], v0);
        atomicAdd(&acc[p1 >> 20], v1);
        atomicAdd(&acc[p2 >> 20], v2);
        atomicAdd(&acc[p3 >> 20], v3);
    }
    for (; e < e1; e += BT) {
        unsigned p = packed[e];
        atomicAdd(&acc[p >> 20], y[p & 0xFFFFFu]);
    }
    __syncthreads();
    int base = j << BSH;
    for (int t = threadIdx.x; t < BSZ; t += BT) {
        int v = base + t;
        if (v < N) {
            float d = dinv[v];
            float agg = d * (acc[t] + y[v]);
            float z = 0.f;
            for (int f = 0; f < F; ++f) {
                float h = fmaf(w1s[f], agg, b1s[f]);
                h = fmaxf(h, 0.f);
                z = fmaf(h, w2s[f], z);
            }
            zy[v] = z * d;
        }
    }
}

// Layer-2 aggregate (LDS) -> out = dinv*(acc + zy) + b2.
__global__ void k_out(const unsigned* __restrict__ packed,
                      const unsigned* __restrict__ bstart,
                      const float* __restrict__ zy,
                      const float* __restrict__ dinv,
                      const float* __restrict__ b2,
                      float* __restrict__ out, int N) {
    int j = blockIdx.x;
    __shared__ float acc[BSZ];
    for (int t = threadIdx.x; t < BSZ; t += BT) acc[t] = 0.f;
    __syncthreads();
    unsigned e0 = bstart[j], e1 = bstart[j + 1];
    unsigned e = e0 + threadIdx.x;
    for (; e + 3u * BT < e1; e += 4u * BT) {
        unsigned p0 = packed[e], p1 = packed[e + BT];
        unsigned p2 = packed[e + 2u * BT], p3 = packed[e + 3u * BT];
        float v0 = zy[p0 & 0xFFFFFu], v1 = zy[p1 & 0xFFFFFu];
        float v2 = zy[p2 & 0xFFFFFu], v3 = zy[p3 & 0xFFFFFu];
        atomicAdd(&acc[p0 >> 20], v0);
        atomicAdd(&acc[p1 >> 20], v1);
        atomicAdd(&acc[p2 >> 20], v2);
        atomicAdd(&acc[p3 >> 20], v3);
    }
    for (; e < e1; e += BT) {
        unsigned p = packed[e];
        atomicAdd(&acc[p >> 20], zy[p & 0xFFFFFu]);
    }
    __syncthreads();
    int base = j << BSH;
    for (int t = threadIdx.x; t < BSZ; t += BT) {
        int v = base + t;
        if (v < N)
            out[v] = fmaf(dinv[v], acc[t] + zy[v], b2[0]);
    }
}

// ===================== fallback: global-atomic pipeline ==================

__global__ void f_zero3(float* __restrict__ a, float* __restrict__ b,
                        float* __restrict__ c, int N) {
    int i = blockIdx.x * blockDim.x + threadIdx.x;
    int stride = gridDim.x * blockDim.x;
    for (int v = i; v < N; v += stride) { a[v] = 0.f; b[v] = 0.f; c[v] = 0.f; }
}
__global__ void f_deg(const int* __restrict__ dst, int E, float* __restrict__ degf) {
    int i = blockIdx.x * blockDim.x + threadIdx.x;
    int stride = gridDim.x * blockDim.x;
    for (int e = i; e < E; e += stride) atomicAdd(&degf[dst[e]], 1.0f);
}
__global__ void f_dinv(float* __restrict__ d, int N) {
    int v = blockIdx.x * blockDim.x + threadIdx.x;
    if (v < N) d[v] = rsqrtf(d[v] + 1.0f);
}
__global__ void f_edge1(const int* __restrict__ src, const int* __restrict__ dst,
                        const float* __restrict__ x, const float* __restrict__ dinv,
                        float* __restrict__ acc1, int E) {
    int i = blockIdx.x * blockDim.x + threadIdx.x;
    int stride = gridDim.x * blockDim.x;
    for (int e = i; e < E; e += stride) {
        int s = src[e];
        atomicAdd(&acc1[dst[e]], x[s] * dinv[s]);
    }
}
__global__ void f_node2(const float* __restrict__ dinv, const float* __restrict__ acc1,
                        const float* __restrict__ x, const float* __restrict__ W1,
                        const float* __restrict__ b1, const float* __restrict__ W2,
                        float* __restrict__ zy, int N, int F) {
    int v = blockIdx.x * blockDim.x + threadIdx.x;
    if (v < N) {
        float d = dinv[v];
        float agg = d * (acc1[v] + x[v] * d);
        float z = 0.f;
        for (int f = 0; f < F; ++f) {
            float h = fmaf(W1[f], agg, b1[f]);
            h = h > 0.f ? h : 0.f;
            z = fmaf(h, W2[f], z);
        }
        zy[v] = z * d;
    }
}
__global__ void f_edge2(const int* __restrict__ src, const int* __restrict__ dst,
                        const float* __restrict__ zy, float* __restrict__ out, int E) {
    int i = blockIdx.x * blockDim.x + threadIdx.x;
    int stride = gridDim.x * blockDim.x;
    for (int e = i; e < E; e += stride) atomicAdd(&out[dst[e]], zy[src[e]]);
}
__global__ void f_node3(const float* __restrict__ dinv, const float* __restrict__ zy,
                        const float* __restrict__ b2, float* __restrict__ out, int N) {
    int v = blockIdx.x * blockDim.x + threadIdx.x;
    if (v < N) out[v] = fmaf(dinv[v], out[v] + zy[v], b2[0]);
}

// ===================== launch ===========================================

extern "C" void kernel_launch(void* const* d_in, const int* in_sizes, int n_in,
                              void* d_out, int out_size, void* d_ws, size_t ws_size,
                              hipStream_t stream) {
    const float* x  = (const float*)d_in[0];
    const int*   ei = (const int*)d_in[1];   // harness passes integers as int32
    const float* W1 = (const float*)d_in[2];
    const float* b1 = (const float*)d_in[3];
    const float* W2 = (const float*)d_in[4];
    const float* b2 = (const float*)d_in[5];
    float* out = (float*)d_out;

    const int N = in_sizes[0];
    const int E = in_sizes[1] / 2;
    const int F = in_sizes[2];

    const int* src = ei;
    const int* dst = ei + E;

    const int NB = (N + BSZ - 1) >> BSH;

    // workspace: [packed E | bh NB*PB | totals NB | bstart NB+1 | dinv N | y N | zy N]
    size_t off_packed = 0;
    size_t off_bh     = off_packed + (size_t)E * 4;
    size_t off_tot    = off_bh + (size_t)NB * PB * 4;
    size_t off_bs     = off_tot + (size_t)NB * 4;
    size_t off_dinv   = off_bs + (size_t)(NB + 1) * 4;
    size_t off_y      = off_dinv + (size_t)N * 4;
    size_t off_zy     = off_y + (size_t)N * 4;
    size_t need       = off_zy + (size_t)N * 4;

    bool ok = (ws_size >= need) && (NB >= 1) && (NB <= 256) &&
              (N <= (1 << 20)) && (F <= 64) && (E > 0);

    char* ws = (char*)d_ws;
    if (ok) {
        unsigned* packed = (unsigned*)(ws + off_packed);
        unsigned* bh     = (unsigned*)(ws + off_bh);
        unsigned* totals = (unsigned*)(ws + off_tot);
        unsigned* bstart = (unsigned*)(ws + off_bs);
        float*    dinv   = (float*)(ws + off_dinv);
        float*    y      = (float*)(ws + off_y);
        float*    zy     = (float*)(ws + off_zy);

        int per = (E + PB - 1) / PB;

        k_hist   <<<PB, 256, 0, stream>>>(dst, E, per, bh, NB);
        k_colscan<<<NB, 256, 0, stream>>>(bh, totals);
        k_scantot<<<1, 256, 0, stream>>>(totals, bstart, NB);
        k_scatter<<<PB, 256, 0, stream>>>(src, dst, E, per, bh, bstart, packed, NB);
        k_deg    <<<NB, BT, 0, stream>>>(packed, bstart, x, dinv, y, N);
        k_acc1   <<<NB, BT, 0, stream>>>(packed, bstart, y, dinv, W1, b1, W2, zy, N, F);
        k_out    <<<NB, BT, 0, stream>>>(packed, bstart, zy, dinv, b2, out, N);
    } else {
        // fallback: verified global-atomic path (needs 12 MB)
        float* dinv = (float*)(ws);
        float* acc1 = (float*)(ws + (size_t)N * 4);
        float* zy   = (float*)(ws + (size_t)N * 8);
        int nodeBlocks = (N + THREADS - 1) / THREADS;
        int edgeBlocks = (E + THREADS - 1) / THREADS;
        if (edgeBlocks > 2048) edgeBlocks = 2048;
        f_zero3<<<2048, THREADS, 0, stream>>>(dinv, acc1, out, N);
        f_deg  <<<edgeBlocks, THREADS, 0, stream>>>(dst, E, dinv);
        f_dinv <<<nodeBlocks, THREADS, 0, stream>>>(dinv, N);
        f_edge1<<<edgeBlocks, THREADS, 0, stream>>>(src, dst, x, dinv, acc1, E);
        f_node2<<<nodeBlocks, THREADS, 0, stream>>>(dinv, acc1, x, W1, b1, W2, zy, N, F);
        f_edge2<<<edgeBlocks, THREADS, 0, stream>>>(src, dst, zy, out, E);
        f_node3<<<nodeBlocks, THREADS, 0, stream>>>(dinv, zy, b2, out, N);
    }
}